// Round 4
// baseline (604.700 us; speedup 1.0000x reference)
//
#include <hip/hip_runtime.h>
#include <cstddef>

#define LN_EPS 1e-5f

typedef unsigned short u16;
typedef short short8 __attribute__((ext_vector_type(8)));
typedef float f32x4 __attribute__((ext_vector_type(4)));

__device__ __forceinline__ u16 f2bf(float f) {
    unsigned int u = __float_as_uint(f);
    u = (u + 0x7FFFu + ((u >> 16) & 1u)) >> 16;
    return (u16)u;
}
__device__ __forceinline__ float bf2f(u16 h) {
    return __uint_as_float((unsigned int)h << 16);
}
// packed RNE f32x2 -> bf16x2 (lo = a, hi = b)
__device__ __forceinline__ unsigned int pk_bf16(float a, float b) {
    unsigned int r;
    asm("v_cvt_pk_bf16_f32 %0, %1, %2" : "=v"(r) : "v"(a), "v"(b));
    return r;
}

// ---------------------------------------------------------------------------
// Multi-tensor fp32 -> bf16 convert (weights + inputs), one launch.
// ---------------------------------------------------------------------------
struct CvtDesc {
    const float* src[16];
    u16* dst[16];
    int n4[16];
};
__global__ __launch_bounds__(256) void cvt_multi(CvtDesc d) {
    const int t = blockIdx.x * 256 + threadIdx.x;
    const int i = blockIdx.y;
    if (t >= d.n4[i]) return;
    const float4 v = ((const float4*)d.src[i])[t];
    ushort4 o;
    o.x = f2bf(v.x); o.y = f2bf(v.y); o.z = f2bf(v.z); o.w = f2bf(v.w);
    ((ushort4*)d.dst[i])[t] = o;
}

// ---------------------------------------------------------------------------
// bf16 MFMA NT GEMM, BMxBN tile, 4 waves (2x2), BK=32, 16x16x32 MFMA.
// LDS rows padded to 40 u16; K-loop register-prefetches the next chunk.
// C = scale*(A@B^T + bias) + res1 + res2 (+relu). Outputs fp32 and/or bf16.
// ---------------------------------------------------------------------------
template<int BM, int BN>
__global__ __launch_bounds__(256) void mfma_gemm(
    const u16* __restrict__ A, int lda,
    const u16* __restrict__ B, int ldb,
    float* __restrict__ Cf, u16* __restrict__ Ch, int ldc,
    const float* __restrict__ bias,
    const float* __restrict__ res1, const float* __restrict__ res2,
    float scale, int relu, int K)
{
    constexpr int MF = BM / 32;
    constexpr int NF = BN / 32;
    constexpr int MC = BM / 64;
    constexpr int NC = BN / 64;
    __shared__ u16 As[BM * 40];
    __shared__ u16 Bs[BN * 40];

    const int tid = threadIdx.x;
    const int wave = tid >> 6, lane = tid & 63;
    const int wm = wave >> 1, wn = wave & 1;
    const int m0 = blockIdx.y * BM, n0 = blockIdx.x * BN;

    f32x4 acc[MF][NF];
#pragma unroll
    for (int mf = 0; mf < MF; ++mf)
#pragma unroll
        for (int nf = 0; nf < NF; ++nf) acc[mf][nf] = (f32x4){0.f, 0.f, 0.f, 0.f};

    const int ar = tid >> 2, ac = (tid & 3) * 8;
    const int ml = lane & 15, kq = lane >> 4;

    short8 aN[MC], bN[NC];
#pragma unroll
    for (int c = 0; c < MC; ++c)
        aN[c] = *(const short8*)&A[(size_t)(m0 + ar + c * 64) * lda + ac];
#pragma unroll
    for (int c = 0; c < NC; ++c)
        bN[c] = *(const short8*)&B[(size_t)(n0 + ar + c * 64) * ldb + ac];

    for (int k0 = 0; k0 < K; k0 += 32) {
        short8 aS[MC], bS[NC];
#pragma unroll
        for (int c = 0; c < MC; ++c) aS[c] = aN[c];
#pragma unroll
        for (int c = 0; c < NC; ++c) bS[c] = bN[c];
        if (k0 + 32 < K) {
#pragma unroll
            for (int c = 0; c < MC; ++c)
                aN[c] = *(const short8*)&A[(size_t)(m0 + ar + c * 64) * lda + k0 + 32 + ac];
#pragma unroll
            for (int c = 0; c < NC; ++c)
                bN[c] = *(const short8*)&B[(size_t)(n0 + ar + c * 64) * ldb + k0 + 32 + ac];
        }
        __syncthreads();
#pragma unroll
        for (int c = 0; c < MC; ++c) *(short8*)&As[(ar + c * 64) * 40 + ac] = aS[c];
#pragma unroll
        for (int c = 0; c < NC; ++c) *(short8*)&Bs[(ar + c * 64) * 40 + ac] = bS[c];
        __syncthreads();

        short8 af[MF], bfr[NF];
#pragma unroll
        for (int mf = 0; mf < MF; ++mf)
            af[mf] = *(const short8*)&As[(wm * (BM / 2) + mf * 16 + ml) * 40 + kq * 8];
#pragma unroll
        for (int nf = 0; nf < NF; ++nf)
            bfr[nf] = *(const short8*)&Bs[(wn * (BN / 2) + nf * 16 + ml) * 40 + kq * 8];
#pragma unroll
        for (int mf = 0; mf < MF; ++mf)
#pragma unroll
            for (int nf = 0; nf < NF; ++nf)
                acc[mf][nf] = __builtin_amdgcn_mfma_f32_16x16x32_bf16(
                    af[mf], bfr[nf], acc[mf][nf], 0, 0, 0);
    }

    const int rq = lane >> 4;
#pragma unroll
    for (int mf = 0; mf < MF; ++mf)
#pragma unroll
        for (int nf = 0; nf < NF; ++nf) {
            const int col = n0 + wn * (BN / 2) + nf * 16 + ml;
            const float bv = bias ? bias[col] : 0.f;
#pragma unroll
            for (int r = 0; r < 4; ++r) {
                const int row = m0 + wm * (BM / 2) + mf * 16 + rq * 4 + r;
                float v = scale * (acc[mf][nf][r] + bv);
                const size_t idx = (size_t)row * ldc + col;
                if (res1) v += res1[idx];
                if (res2) v += res2[idx];
                if (relu) v = fmaxf(v, 0.f);
                if (Cf) Cf[idx] = v;
                if (Ch) Ch[idx] = f2bf(v);
            }
        }
}

// ---------------------------------------------------------------------------
// Split-S flash attention. Block = 64 q-rows x one S-chunk, 4 waves; wave w
// owns rows w*16..w*16+15 end-to-end (in-register softmax via shfl over the
// 16-lane ml group; per-wave-private St slice for the PV A-operand).
//
// WITHIN-64 COLUMN PERMUTATION: score col (nf,ml) [logical s = 16*nf + ml]
// is stored at PHYSICAL position p = 4*ml + nf, so each lane's 4 values per
// row are contiguous 8 bytes -> cvt_pk_bf16 pairs + one b64 store replaces
// 16 scalar stores. PV is permutation-invariant because vtrans stages V in
// the SAME physical order. probs (NEED_W) are written permuted; avg_softmax
// un-permutes at its final scatter write.
//
// Each block writes UN-normalized partial O (fp32) + per-row (m,l) to
// workspace; attn_merge combines chunks. grid = (L/64, 16 bh, nchunks).
// ---------------------------------------------------------------------------
template<bool NEED_W>
__global__ __launch_bounds__(256) void attn_flash64(
    const u16* __restrict__ Q, int ldq,
    const u16* __restrict__ Kp, int ldk,
    const u16* __restrict__ vT,
    u16* __restrict__ scores,
    float* __restrict__ Of, float2* __restrict__ pml,
    int L, int S, int CS)
{
    __shared__ u16 Ks[64 * 72];
    __shared__ u16 Vt[64 * 72];
    __shared__ u16 St[4][16 * 72];

    const int tid = threadIdx.x;
    const int wave = tid >> 6, lane = tid & 63;
    const int ml = lane & 15, rq = lane >> 4;
    const int i0 = blockIdx.x * 64;
    const int bz = blockIdx.y, bb = bz & 1, hh = bz >> 1;
    const int chunk = blockIdx.z;
    const int cs0 = chunk * CS;
    u16* Sb = NEED_W ? scores + (size_t)bz * L * S + (size_t)i0 * S : nullptr;
    const u16* Vbase = vT + (size_t)bz * 64 * S;

    // Q fragments for this wave's 16 rows (one-time, direct from global)
    const int qrow = i0 + wave * 16 + ml;
    const short8 qf0 = *(const short8*)&Q[(size_t)(qrow * 2 + bb) * ldq + hh * 64 + rq * 8];
    const short8 qf1 = *(const short8*)&Q[(size_t)(qrow * 2 + bb) * ldq + hh * 64 + 32 + rq * 8];

    float mrun[4], lrun[4];
    f32x4 acc[4];
#pragma unroll
    for (int r = 0; r < 4; ++r) {
        mrun[r] = -1e30f; lrun[r] = 0.f;
        acc[r] = (f32x4){0.f, 0.f, 0.f, 0.f};
    }

    const int sr0 = tid >> 3, dc0 = (tid & 7) * 8;
    const int sr1 = (tid + 256) >> 3, dc1 = ((tid + 256) & 7) * 8;

    // prefetch first tile of this chunk into registers
    short8 kr0 = *(const short8*)&Kp[(size_t)((cs0 + sr0) * 2 + bb) * ldk + hh * 64 + dc0];
    short8 kr1 = *(const short8*)&Kp[(size_t)((cs0 + sr1) * 2 + bb) * ldk + hh * 64 + dc1];
    short8 vr0 = *(const short8*)&Vbase[(size_t)sr0 * S + cs0 + dc0];
    short8 vr1 = *(const short8*)&Vbase[(size_t)sr1 * S + cs0 + dc1];

    u16* Sw = St[wave];

    for (int k0 = cs0; k0 < cs0 + CS; k0 += 64) {
        __syncthreads();   // prev tile's Ks/Vt reads complete
        *(short8*)&Ks[sr0 * 72 + dc0] = kr0;
        *(short8*)&Ks[sr1 * 72 + dc1] = kr1;
        *(short8*)&Vt[sr0 * 72 + dc0] = vr0;
        *(short8*)&Vt[sr1 * 72 + dc1] = vr1;
        if (k0 + 64 < cs0 + CS) {
            const int kn = k0 + 64;
            kr0 = *(const short8*)&Kp[(size_t)((kn + sr0) * 2 + bb) * ldk + hh * 64 + dc0];
            kr1 = *(const short8*)&Kp[(size_t)((kn + sr1) * 2 + bb) * ldk + hh * 64 + dc1];
            vr0 = *(const short8*)&Vbase[(size_t)sr0 * S + kn + dc0];
            vr1 = *(const short8*)&Vbase[(size_t)sr1 * S + kn + dc1];
        }
        __syncthreads();   // staged tile visible

        // ---- QK^T: 4 col-fragments x (K=64 as 2 MFMAs), scores in regs
        f32x4 sc[4];
#pragma unroll
        for (int nf = 0; nf < 4; ++nf) {
            const short8 kf0 = *(const short8*)&Ks[(nf * 16 + ml) * 72 + rq * 8];
            const short8 kf1 = *(const short8*)&Ks[(nf * 16 + ml) * 72 + 32 + rq * 8];
            f32x4 s = (f32x4){0.f, 0.f, 0.f, 0.f};
            s = __builtin_amdgcn_mfma_f32_16x16x32_bf16(qf0, kf0, s, 0, 0, 0);
            s = __builtin_amdgcn_mfma_f32_16x16x32_bf16(qf1, kf1, s, 0, 0, 0);
#pragma unroll
            for (int r = 0; r < 4; ++r) s[r] *= 0.125f;
            sc[nf] = s;
        }

        // ---- stream raw bf16 scores to global, packed, permuted-within-64
        if (NEED_W) {
#pragma unroll
            for (int r = 0; r < 4; ++r) {
                const unsigned int pk0 = pk_bf16(sc[0][r], sc[1][r]);
                const unsigned int pk1 = pk_bf16(sc[2][r], sc[3][r]);
                *(uint2*)&Sb[(size_t)(wave * 16 + rq * 4 + r) * S + k0 + ml * 4] =
                    make_uint2(pk0, pk1);
            }
        }

        // ---- per-row tile max (registers + shfl over ml group)
        float tm[4];
#pragma unroll
        for (int r = 0; r < 4; ++r)
            tm[r] = fmaxf(fmaxf(sc[0][r], sc[1][r]), fmaxf(sc[2][r], sc[3][r]));
#pragma unroll
        for (int mk = 1; mk < 16; mk <<= 1)
#pragma unroll
            for (int r = 0; r < 4; ++r)
                tm[r] = fmaxf(tm[r], __shfl_xor(tm[r], mk));

        float alpha[4], mn[4];
#pragma unroll
        for (int r = 0; r < 4; ++r) {
            mn[r] = fmaxf(mrun[r], tm[r]);
            alpha[r] = __expf(mrun[r] - mn[r]);
            mrun[r] = mn[r];
        }

        // ---- exp (once), row-sum, P -> private St slice (packed, permuted)
        float rs[4];
#pragma unroll
        for (int r = 0; r < 4; ++r) {
            const float p0 = __expf(sc[0][r] - mn[r]);
            const float p1 = __expf(sc[1][r] - mn[r]);
            const float p2 = __expf(sc[2][r] - mn[r]);
            const float p3 = __expf(sc[3][r] - mn[r]);
            rs[r] = (p0 + p1) + (p2 + p3);
            const unsigned int pk0 = pk_bf16(p0, p1);
            const unsigned int pk1 = pk_bf16(p2, p3);
            *(uint2*)&Sw[(rq * 4 + r) * 72 + ml * 4] = make_uint2(pk0, pk1);
        }
#pragma unroll
        for (int mk = 1; mk < 16; mk <<= 1)
#pragma unroll
            for (int r = 0; r < 4; ++r)
                rs[r] += __shfl_xor(rs[r], mk);
#pragma unroll
        for (int r = 0; r < 4; ++r)
            lrun[r] = lrun[r] * alpha[r] + rs[r];

        // ---- O rescale + PV (A from private St, same-wave in-order DS)
#pragma unroll
        for (int df = 0; df < 4; ++df)
#pragma unroll
            for (int r = 0; r < 4; ++r)
                acc[df][r] *= alpha[r];
#pragma unroll
        for (int kc = 0; kc < 2; ++kc) {
            const short8 afr = *(const short8*)&Sw[ml * 72 + kc * 32 + rq * 8];
#pragma unroll
            for (int df = 0; df < 4; ++df) {
                const short8 bfr = *(const short8*)&Vt[(df * 16 + ml) * 72 + kc * 32 + rq * 8];
                acc[df] = __builtin_amdgcn_mfma_f32_16x16x32_bf16(afr, bfr, acc[df], 0, 0, 0);
            }
        }
    }

    // ---- write un-normalized partial O + per-row (m,l)
#pragma unroll
    for (int df = 0; df < 4; ++df)
#pragma unroll
        for (int r = 0; r < 4; ++r) {
            const int i = i0 + wave * 16 + rq * 4 + r;
            Of[((size_t)(chunk * 16 + bz) * L + i) * 64 + df * 16 + ml] = acc[df][r];
        }
    if (ml == 0) {
#pragma unroll
        for (int r = 0; r < 4; ++r)
            pml[(size_t)chunk * 16 * L + (size_t)bz * L + i0 + wave * 16 + rq * 4 + r] =
                make_float2(mrun[r], lrun[r]);
    }
}

// ---------------------------------------------------------------------------
// Merge split-S partials: att = (sum_c e^{m_c-M} O_c) / (sum_c e^{m_c-M} l_c),
// stats = (M, 1/l_total). Block of 256 handles 4 rows (64 lanes per row).
// grid = 16*L/4.
// ---------------------------------------------------------------------------
template<bool NEED_W>
__global__ __launch_bounds__(256) void attn_merge(
    const float* __restrict__ Of, const float2* __restrict__ pml,
    u16* __restrict__ att, float2* __restrict__ stats, int L, int nchunks)
{
    const int tid = threadIdx.x;
    const int g = blockIdx.x * 4 + (tid >> 6);   // row id in [0, 16*L)
    const int d = tid & 63;
    const int bz = g / L, i = g - bz * L;
    const int bb = bz & 1, hh = bz >> 1;

    float M = -1e30f;
    for (int c = 0; c < nchunks; ++c)
        M = fmaxf(M, pml[(size_t)c * 16 * L + g].x);
    float T = 0.f, O = 0.f;
    for (int c = 0; c < nchunks; ++c) {
        const float2 ml_ = pml[(size_t)c * 16 * L + g];
        const float w = __expf(ml_.x - M);
        T += ml_.y * w;
        O += w * Of[((size_t)(c * 16 + bz) * L + i) * 64 + d];
    }
    const float invT = 1.0f / T;
    att[((size_t)i * 2 + bb) * 512 + hh * 64 + d] = f2bf(O * invT);
    if (NEED_W && d == 0)
        stats[(size_t)bz * L + i] = make_float2(M, invT);
}

// ---------------------------------------------------------------------------
// One-time V transpose: vT[bh][d][tile*64+p] = V[(s*2+b)*ldv + h*64 + d]
// with logical s = tile*64 + (p>>2) + 16*(p&3)  (within-64 permutation that
// matches attn_flash64's P layout).
// ---------------------------------------------------------------------------
__global__ __launch_bounds__(256) void vtrans(
    const u16* __restrict__ V, int ldv, u16* __restrict__ vT, int S)
{
    __shared__ u16 Vs[64 * 72];
    const int tid = threadIdx.x;
    const int s0 = blockIdx.x * 64;
    const int bh = blockIdx.y, b = bh & 1, h = bh >> 1;

#pragma unroll
    for (int c = 0; c < 2; ++c) {
        const int idx = tid + c * 256;
        const int sr = idx >> 3, dc = (idx & 7) * 8;
        *(short8*)&Vs[sr * 72 + dc] =
            *(const short8*)&V[(size_t)((s0 + sr) * 2 + b) * ldv + h * 64 + dc];
    }
    __syncthreads();
#pragma unroll
    for (int c = 0; c < 2; ++c) {
        const int idx = tid + c * 256;
        const int dr = idx >> 3, sc = (idx & 7) * 8;
        short8 o;
#pragma unroll
        for (int j = 0; j < 8; ++j) {
            const int p = sc + j;
            o[j] = (short)Vs[((p >> 2) + 16 * (p & 3)) * 72 + dr];
        }
        *(short8*)&vT[(size_t)bh * 64 * S + (size_t)dr * S + s0 + sc] = o;
    }
}

// ---------------------------------------------------------------------------
// Head-average of (stats-normalized) probs from RAW scores + second softmax
// -> fp32 out (1 or 2 copies). grid = 2*L, blockIdx.x = b*L + i.
// probs are stored permuted-within-64; reads stay coalesced (all reductions
// are permutation-invariant) and the final write un-permutes.
// ---------------------------------------------------------------------------
__global__ __launch_bounds__(256) void avg_softmax_f(
    const u16* __restrict__ P, const float2* __restrict__ st, int L, int S,
    float* __restrict__ out1, float* __restrict__ out2)
{
    __shared__ float red[256];
    const int tid = threadIdx.x;
    const bool act = tid * 8 < S;
    const int b = blockIdx.x / L, i = blockIdx.x % L;
    const size_t LS = (size_t)L * S;

    float acc[8] = {};
    if (act) {
#pragma unroll
        for (int h = 0; h < 8; ++h) {
            const int bh = h * 2 + b;
            const float2 s = st[(size_t)bh * L + i];
            const short8 r8 = *(const short8*)&P[(size_t)bh * LS + (size_t)i * S + tid * 8];
#pragma unroll
            for (int j = 0; j < 8; ++j)
                acc[j] += __expf(bf2f((u16)r8[j]) - s.x) * s.y;
        }
#pragma unroll
        for (int j = 0; j < 8; ++j) acc[j] *= 0.125f;
    }
    float lmax = -1e30f;
    if (act) {
#pragma unroll
        for (int j = 0; j < 8; ++j) lmax = fmaxf(lmax, acc[j]);
    }
    red[tid] = lmax; __syncthreads();
    for (int s = 128; s; s >>= 1) {
        if (tid < s) red[tid] = fmaxf(red[tid], red[tid + s]);
        __syncthreads();
    }
    const float mx = red[0]; __syncthreads();
    float e[8];
    float ls = 0.f;
    if (act) {
#pragma unroll
        for (int j = 0; j < 8; ++j) { e[j] = __expf(acc[j] - mx); ls += e[j]; }
    }
    red[tid] = ls; __syncthreads();
    for (int s = 128; s; s >>= 1) {
        if (tid < s) red[tid] += red[tid + s];
        __syncthreads();
    }
    const float inv = 1.0f / red[0];
    if (act) {
        // un-permute: physical p_in = (tid&7)*8+j -> true col c within 64-tile
        const size_t base = (size_t)blockIdx.x * S + (size_t)(tid >> 3) * 64;
        const int t2 = (tid & 7) * 2;
#pragma unroll
        for (int j = 0; j < 8; ++j) {
            const int c = t2 + (j >> 2) + 16 * (j & 3);
            const float v = e[j] * inv;
            out1[base + c] = v;
            if (out2) out2[base + c] = v;
        }
    }
}

// ---------------------------------------------------------------------------
// LayerNorm over rows of 512; fp32 out + optional bf16 out.
// ---------------------------------------------------------------------------
__global__ __launch_bounds__(256) void ln512(
    const float* __restrict__ X, const float* __restrict__ g,
    const float* __restrict__ be, float* __restrict__ Yf, u16* __restrict__ Yb)
{
    __shared__ float red[256];
    const int r = blockIdx.x, tid = threadIdx.x;
    const float* xr = X + (size_t)r * 512;
    const float x0 = xr[tid], x1 = xr[tid + 256];
    red[tid] = x0 + x1; __syncthreads();
    for (int st = 128; st; st >>= 1) {
        if (tid < st) red[tid] += red[tid + st];
        __syncthreads();
    }
    const float mean = red[0] * (1.0f / 512.0f); __syncthreads();
    const float d0 = x0 - mean, d1 = x1 - mean;
    red[tid] = d0 * d0 + d1 * d1; __syncthreads();
    for (int st = 128; st; st >>= 1) {
        if (tid < st) red[tid] += red[tid + st];
        __syncthreads();
    }
    const float rstd = rsqrtf(red[0] * (1.0f / 512.0f) + LN_EPS);
    const float y0 = d0 * rstd * g[tid] + be[tid];
    const float y1 = d1 * rstd * g[tid + 256] + be[tid + 256];
    float* yr = Yf + (size_t)r * 512;
    yr[tid] = y0; yr[tid + 256] = y1;
    if (Yb) {
        u16* yb = Yb + (size_t)r * 512;
        yb[tid] = f2bf(y0); yb[tid + 256] = f2bf(y1);
    }
}

// ---------------------------------------------------------------------------
// pair assembly: inverse map + gather rows to bf16.
// ---------------------------------------------------------------------------
__global__ void init_inv(int* __restrict__ inv) {
    const int i = blockIdx.x * 256 + threadIdx.x;
    if (i < 4096) inv[i] = -1;
}
__global__ void scatter_inv(int* __restrict__ inv, const int* __restrict__ ind, int n) {
    const int i = blockIdx.x * 256 + threadIdx.x;
    if (i < n) inv[ind[i]] = i;
}
__global__ void gather_rows_bf(
    u16* __restrict__ dst, const float* __restrict__ spf,
    const float* __restrict__ ep, const int* __restrict__ ind,
    const int* __restrict__ inv, int total4)
{
    const int e = blockIdx.x * 256 + threadIdx.x;
    if (e >= total4) return;
    const int row = e >> 7, c = e & 127;
    const int j = row >> 1, b = row & 1;
    const int idx = ind[j];
    const int iv = inv[idx];
    const float4* src = (iv >= 0) ? (const float4*)(spf + (size_t)(iv * 2 + b) * 512)
                                  : (const float4*)(ep + (size_t)(idx * 2 + b) * 512);
    const float4 v = src[c];
    ushort4 o; o.x = f2bf(v.x); o.y = f2bf(v.y); o.z = f2bf(v.z); o.w = f2bf(v.w);
    ((ushort4*)dst)[e] = o;
}

// ---------------------------------------------------------------------------
extern "C" void kernel_launch(void* const* d_in, const int* in_sizes, int n_in,
                              void* d_out, int out_size, void* d_ws, size_t ws_size,
                              hipStream_t stream)
{
    (void)in_sizes; (void)n_in; (void)out_size; (void)ws_size;

    const float* in_sp = (const float*)d_in[0];
    const float* in_su = (const float*)d_in[1];
    const float* in_ep = (const float*)d_in[2];
    const int* ind_pair = (const int*)d_in[3];
    const int* ind_e2e  = (const int*)d_in[4];
    const int* ind_n2e  = (const int*)d_in[5];
    const float *Wi_sa  = (const float*)d_in[6],  *bi_sa  = (const float*)d_in[7];
    const float *Wo_sa  = (const float*)d_in[8],  *bo_sa  = (const float*)d_in[9];
    const float *Wi_san = (const float*)d_in[10], *bi_san = (const float*)d_in[11];
    const float *Wo_san = (const float*)d_in[12], *bo_san = (const float*)d_in[13];
    const float *Wi_e2e = (const float*)d_in[14], *bi_e2e = (const float*)d_in[15];
    const float *Wo_e2e = (const float*)d_in[16], *bo_e2e = (const float*)d_in[17];
    const float *Wi_n2e = (const float*)d_in[18], *bi_n2e = (const float*)d_in[19];
    const float *Wo_n2e = (const float*)d_in[20], *bo_n2e = (const float*)d_in[21];
    const float *Wi_n2n = (const float*)d_in[22], *bi_n2n = (const float*)d_in[23];
    const float *Wo_n2n = (const float*)d_in[24], *bo_n2n = (const float*)d_in[25];
    const float *W1  = (const float*)d_in[26], *b1f  = (const float*)d_in[27];
    const float *W2  = (const float*)d_in[28], *b2f  = (const float*)d_in[29];
    const float *W1u = (const float*)d_in[30], *b1fu = (const float*)d_in[31];
    const float *W2u = (const float*)d_in[32], *b2fu = (const float*)d_in[33];
    const float *g1  = (const float*)d_in[34], *g1u = (const float*)d_in[35];
    const float *g2  = (const float*)d_in[36], *g3  = (const float*)d_in[37];
    const float *be1 = (const float*)d_in[38], *be1u = (const float*)d_in[39];
    const float *be2 = (const float*)d_in[40], *be3  = (const float*)d_in[41];

    float* Wf = (float*)d_ws;
    size_t of = 0;
    auto af_ = [&](size_t n) { float* p = Wf + of; of += n; return p; };
    float* spf    = af_((size_t)2048 * 512);
    float* suf    = af_((size_t)512 * 512);
    float* tmp0f  = af_((size_t)2048 * 512);
    float* tmp1f  = af_((size_t)2048 * 512);
    float* upn2ef = af_((size_t)512 * 512);
    float2* stats = (float2*)af_((size_t)2 * 16 * 1024);
    float* Ofp    = af_((size_t)4096 * 16 * 64);          // split-S partial O
    float2* pml   = (float2*)af_((size_t)2 * 4096 * 16);  // split-S partial (m,l)

    u16* Wu = (u16*)(Wf + of);
    size_t ou = 0;
    auto au_ = [&](size_t n) { u16* p = Wu + ou; ou += n; return p; };
    u16* in_spb = au_((size_t)2048 * 512);
    u16* in_sub = au_((size_t)512 * 512);
    u16* spb    = au_((size_t)2048 * 512);
    u16* sub    = au_((size_t)512 * 512);
    u16* ge2eb  = au_((size_t)4096 * 512);
    u16* gn2eb  = au_((size_t)4096 * 512);
    u16* qkvb   = au_((size_t)2048 * 1536);
    u16* kvb    = au_((size_t)4096 * 1024);
    u16* attb   = au_((size_t)2048 * 512);
    u16* tmp1b  = au_((size_t)2048 * 512);
    u16* ffnb   = au_((size_t)2048 * 2048);
    u16* vtb    = au_((size_t)16 * 64 * 2048);
    u16* probs  = au_((size_t)16 * 1024 * 2048);
    u16* wb[14];
    const int wsz[14] = {786432, 262144, 786432, 262144, 786432, 262144, 786432,
                         262144, 786432, 262144, 1048576, 1048576, 1048576, 1048576};
    for (int i = 0; i < 14; ++i) wb[i] = au_((size_t)wsz[i]);
    int* inv = (int*)(Wu + ou);

    float* out_uu = (float*)d_out;
    float* out_up = out_uu + 262144;
    float* out_w1 = out_up + 1048576;
    float* out_w2 = out_w1 + 4194304;
    float* out_w3 = out_w2 + 4194304;
    float* out_w4 = out_w3 + 1048576;

    const dim3 blk(256);

    CvtDesc cd;
    const float* wsrc[14] = {Wi_sa, Wo_sa, Wi_san, Wo_san, Wi_e2e, Wo_e2e, Wi_n2e,
                             Wo_n2e, Wi_n2n, Wo_n2n, W1, W2, W1u, W2u};
    for (int i = 0; i < 14; ++i) { cd.src[i] = wsrc[i]; cd.dst[i] = wb[i]; cd.n4[i] = wsz[i] / 4; }
    cd.src[14] = in_sp; cd.dst[14] = in_spb; cd.n4[14] = 1048576 / 4;
    cd.src[15] = in_su; cd.dst[15] = in_sub; cd.n4[15] = 262144 / 4;
    cvt_multi<<<dim3(1024, 16), blk, 0, stream>>>(cd);

    init_inv<<<16, blk, 0, stream>>>(inv);
    scatter_inv<<<4, blk, 0, stream>>>(inv, ind_pair, 1024);

    auto gemm = [&](int tile, const u16* A, int lda, const u16* B, int ldb,
                    float* Cf, u16* Ch, int ldc,
                    const float* bias, const float* r1, const float* r2,
                    float scale, int relu, int M, int N, int K) {
        if (tile == 64)
            mfma_gemm<64, 64><<<dim3(N / 64, M / 64), blk, 0, stream>>>(
                A, lda, B, ldb, Cf, Ch, ldc, bias, r1, r2, scale, relu, K);
        else
            mfma_gemm<128, 128><<<dim3(N / 128, M / 128), blk, 0, stream>>>(
                A, lda, B, ldb, Cf, Ch, ldc, bias, r1, r2, scale, relu, K);
    };
    // attention core: vtrans + split-S flash + merge
    auto attn = [&](const u16* Q, int ldq, const u16* Kp, int ldk,
                    const u16* V, int ldv, int L, int S, bool needW, int nchunks) {
        vtrans<<<dim3(S / 64, 16), blk, 0, stream>>>(V, ldv, vtb, S);
        const int CS = S / nchunks;
        const dim3 g(L / 64, 16, nchunks);
        const dim3 m(16 * L / 4);
        if (needW) {
            attn_flash64<true><<<g, blk, 0, stream>>>(
                Q, ldq, Kp, ldk, vtb, probs, Ofp, pml, L, S, CS);
            attn_merge<true><<<m, blk, 0, stream>>>(Ofp, pml, attb, stats, L, nchunks);
        } else {
            attn_flash64<false><<<g, blk, 0, stream>>>(
                Q, ldq, Kp, ldk, vtb, nullptr, Ofp, pml, L, S, CS);
            attn_merge<false><<<m, blk, 0, stream>>>(Ofp, pml, attb, nullptr, L, nchunks);
        }
    };

    // ================= self-attention (pair) =================
    gemm(128, in_spb, 512, wb[0], 512, nullptr, qkvb, 1536,
         bi_sa, nullptr, nullptr, 1.f, 0, 2048, 1536, 512);
    attn(qkvb, 1536, qkvb + 512, 1536, qkvb + 1024, 1536, 1024, 1024, false, 4);
    gemm(64, attb, 512, wb[1], 512, tmp0f, nullptr, 512,
         bo_sa, in_sp, nullptr, 1.f, 0, 2048, 512, 512);
    ln512<<<2048, blk, 0, stream>>>(tmp0f, g1, be1, spf, spb);

    // ================= self-attention (unary) =================
    gemm(64, in_sub, 512, wb[2], 512, nullptr, qkvb, 1536,
         bi_san, nullptr, nullptr, 1.f, 0, 512, 1536, 512);
    attn(qkvb, 1536, qkvb + 512, 1536, qkvb + 1024, 1536, 256, 256, false, 4);
    gemm(64, attb, 512, wb[3], 512, tmp0f, nullptr, 512,
         bo_san, in_su, nullptr, 1.f, 0, 512, 512, 512);
    ln512<<<512, blk, 0, stream>>>(tmp0f, g1u, be1u, suf, sub);

    // ================= gathers =================
    gather_rows_bf<<<2048, blk, 0, stream>>>(ge2eb, spf, in_ep, ind_e2e, inv, 524288);
    gather_rows_bf<<<2048, blk, 0, stream>>>(gn2eb, spf, in_ep, ind_n2e, inv, 524288);

    // ================= e2e cross-attention =================
    gemm(64, spb, 512, wb[4], 512, nullptr, qkvb, 512,
         bi_e2e, nullptr, nullptr, 1.f, 0, 2048, 512, 512);
    gemm(128, ge2eb, 512, wb[4] + 262144, 512, nullptr, kvb, 1024,
         bi_e2e + 512, nullptr, nullptr, 1.f, 0, 4096, 1024, 512);
    attn(qkvb, 512, kvb, 1024, kvb + 512, 1024, 1024, 2048, true, 4);
    avg_softmax_f<<<2048, blk, 0, stream>>>(probs, stats, 1024, 2048, out_w1, out_w2);
    gemm(64, attb, 512, wb[5], 512, tmp0f, nullptr, 512,
         bo_e2e, spf, nullptr, 2.f, 0, 2048, 512, 512);
    ln512<<<2048, blk, 0, stream>>>(tmp0f, g2, be2, tmp1f, tmp1b);
    // FFN (pair)
    gemm(128, tmp1b, 512, wb[10], 512, nullptr, ffnb, 2048,
         b1f, nullptr, nullptr, 1.f, 1, 2048, 2048, 512);
    gemm(64, ffnb, 2048, wb[11], 2048, tmp0f, nullptr, 512,
         b2f, tmp1f, nullptr, 1.f, 0, 2048, 512, 2048);
    ln512<<<2048, blk, 0, stream>>>(tmp0f, g3, be3, out_up, nullptr);

    // ================= n2e cross-attention =================
    gemm(64, sub, 512, wb[6], 512, nullptr, qkvb, 512,
         bi_n2e, nullptr, nullptr, 1.f, 0, 512, 512, 512);
    gemm(128, gn2eb, 512, wb[6] + 262144, 512, nullptr, kvb, 1024,
         bi_n2e + 512, nullptr, nullptr, 1.f, 0, 4096, 1024, 512);
    attn(qkvb, 512, kvb, 1024, kvb + 512, 1024, 256, 2048, true, 16);
    avg_softmax_f<<<512, blk, 0, stream>>>(probs, stats, 256, 2048, out_w3, nullptr);
    gemm(64, attb, 512, wb[7], 512, upn2ef, nullptr, 512,
         bo_n2e, nullptr, nullptr, 1.f, 0, 512, 512, 512);

    // ================= n2n self-attention =================
    gemm(64, sub, 512, wb[8], 512, nullptr, qkvb, 1536,
         bi_n2n, nullptr, nullptr, 1.f, 0, 512, 1536, 512);
    attn(qkvb, 1536, qkvb + 512, 1536, qkvb + 1024, 1536, 256, 256, true, 4);
    avg_softmax_f<<<512, blk, 0, stream>>>(probs, stats, 256, 256, out_w4, nullptr);
    gemm(64, attb, 512, wb[9], 512, tmp0f, nullptr, 512,
         bo_n2n, suf, upn2ef, 1.f, 0, 512, 512, 512);
    ln512<<<512, blk, 0, stream>>>(tmp0f, g2, be2, tmp1f, tmp1b);
    // FFN (unary)
    gemm(64, tmp1b, 512, wb[12], 512, nullptr, ffnb, 2048,
         b1fu, nullptr, nullptr, 1.f, 1, 512, 2048, 512);
    gemm(64, ffnb, 2048, wb[13], 2048, tmp0f, nullptr, 512,
         b2fu, tmp1f, nullptr, 1.f, 0, 512, 512, 2048);
    ln512<<<512, blk, 0, stream>>>(tmp0f, g3, be3, out_uu, nullptr);
}

// Round 5
// 572.593 us; speedup vs baseline: 1.0561x; 1.0561x over previous
//
#include <hip/hip_runtime.h>
#include <cstddef>

#define LN_EPS 1e-5f

typedef unsigned short u16;
typedef short short8 __attribute__((ext_vector_type(8)));
typedef float f32x4 __attribute__((ext_vector_type(4)));

__device__ __forceinline__ u16 f2bf(float f) {
    unsigned int u = __float_as_uint(f);
    u = (u + 0x7FFFu + ((u >> 16) & 1u)) >> 16;
    return (u16)u;
}
__device__ __forceinline__ float bf2f(u16 h) {
    return __uint_as_float((unsigned int)h << 16);
}
// packed RNE f32x2 -> bf16x2 (lo = a, hi = b)
__device__ __forceinline__ unsigned int pk_bf16(float a, float b) {
    unsigned int r;
    asm("v_cvt_pk_bf16_f32 %0, %1, %2" : "=v"(r) : "v"(a), "v"(b));
    return r;
}

// ---------------------------------------------------------------------------
// Multi-tensor fp32 -> bf16 convert (weights + inputs), one launch.
// ---------------------------------------------------------------------------
struct CvtDesc {
    const float* src[16];
    u16* dst[16];
    int n4[16];
};
__global__ __launch_bounds__(256) void cvt_multi(CvtDesc d) {
    const int t = blockIdx.x * 256 + threadIdx.x;
    const int i = blockIdx.y;
    if (t >= d.n4[i]) return;
    const float4 v = ((const float4*)d.src[i])[t];
    ushort4 o;
    o.x = f2bf(v.x); o.y = f2bf(v.y); o.z = f2bf(v.z); o.w = f2bf(v.w);
    ((ushort4*)d.dst[i])[t] = o;
}

// ---------------------------------------------------------------------------
// bf16 MFMA NT GEMM, BMxBN tile, 4 waves (2x2), BK=64, 16x16x32 MFMA.
// LDS rows padded to 72 u16; K-loop register-prefetches the next chunk.
// BK=64: one barrier pair per 64-K (half of BK=32) -> 2x MFMA per staging
// round-trip; helps the small latency-bound GEMMs (1 block/CU).
// C = scale*(A@B^T + bias) + res1 + res2 (+relu). Outputs fp32 and/or bf16.
// ---------------------------------------------------------------------------
template<int BM, int BN>
__global__ __launch_bounds__(256) void mfma_gemm(
    const u16* __restrict__ A, int lda,
    const u16* __restrict__ B, int ldb,
    float* __restrict__ Cf, u16* __restrict__ Ch, int ldc,
    const float* __restrict__ bias,
    const float* __restrict__ res1, const float* __restrict__ res2,
    float scale, int relu, int K)
{
    constexpr int MF = BM / 32;     // acc fragments per wave (rows)
    constexpr int NF = BN / 32;
    constexpr int MP = BM / 32;     // staging passes for A (32 rows x 64 cols each)
    constexpr int NP = BN / 32;
    __shared__ u16 As[BM * 72];
    __shared__ u16 Bs[BN * 72];

    const int tid = threadIdx.x;
    const int wave = tid >> 6, lane = tid & 63;
    const int wm = wave >> 1, wn = wave & 1;
    const int m0 = blockIdx.y * BM, n0 = blockIdx.x * BN;

    f32x4 acc[MF][NF];
#pragma unroll
    for (int mf = 0; mf < MF; ++mf)
#pragma unroll
        for (int nf = 0; nf < NF; ++nf) acc[mf][nf] = (f32x4){0.f, 0.f, 0.f, 0.f};

    const int ar = tid >> 3, ac = (tid & 7) * 8;   // 32 rows x 64 cols per pass
    const int ml = lane & 15, kq = lane >> 4;

    short8 aN[MP], bN[NP];
#pragma unroll
    for (int c = 0; c < MP; ++c)
        aN[c] = *(const short8*)&A[(size_t)(m0 + ar + c * 32) * lda + ac];
#pragma unroll
    for (int c = 0; c < NP; ++c)
        bN[c] = *(const short8*)&B[(size_t)(n0 + ar + c * 32) * ldb + ac];

    for (int k0 = 0; k0 < K; k0 += 64) {
        short8 aS[MP], bS[NP];
#pragma unroll
        for (int c = 0; c < MP; ++c) aS[c] = aN[c];
#pragma unroll
        for (int c = 0; c < NP; ++c) bS[c] = bN[c];
        if (k0 + 64 < K) {
#pragma unroll
            for (int c = 0; c < MP; ++c)
                aN[c] = *(const short8*)&A[(size_t)(m0 + ar + c * 32) * lda + k0 + 64 + ac];
#pragma unroll
            for (int c = 0; c < NP; ++c)
                bN[c] = *(const short8*)&B[(size_t)(n0 + ar + c * 32) * ldb + k0 + 64 + ac];
        }
        __syncthreads();
#pragma unroll
        for (int c = 0; c < MP; ++c) *(short8*)&As[(ar + c * 32) * 72 + ac] = aS[c];
#pragma unroll
        for (int c = 0; c < NP; ++c) *(short8*)&Bs[(ar + c * 32) * 72 + ac] = bS[c];
        __syncthreads();

        short8 af0[MF], af1[MF], bf0[NF], bf1[NF];
#pragma unroll
        for (int mf = 0; mf < MF; ++mf) {
            const int base = (wm * (BM / 2) + mf * 16 + ml) * 72 + kq * 8;
            af0[mf] = *(const short8*)&As[base];
            af1[mf] = *(const short8*)&As[base + 32];
        }
#pragma unroll
        for (int nf = 0; nf < NF; ++nf) {
            const int base = (wn * (BN / 2) + nf * 16 + ml) * 72 + kq * 8;
            bf0[nf] = *(const short8*)&Bs[base];
            bf1[nf] = *(const short8*)&Bs[base + 32];
        }
#pragma unroll
        for (int mf = 0; mf < MF; ++mf)
#pragma unroll
            for (int nf = 0; nf < NF; ++nf) {
                acc[mf][nf] = __builtin_amdgcn_mfma_f32_16x16x32_bf16(
                    af0[mf], bf0[nf], acc[mf][nf], 0, 0, 0);
                acc[mf][nf] = __builtin_amdgcn_mfma_f32_16x16x32_bf16(
                    af1[mf], bf1[nf], acc[mf][nf], 0, 0, 0);
            }
    }

    const int rq = lane >> 4;
#pragma unroll
    for (int mf = 0; mf < MF; ++mf)
#pragma unroll
        for (int nf = 0; nf < NF; ++nf) {
            const int col = n0 + wn * (BN / 2) + nf * 16 + ml;
            const float bv = bias ? bias[col] : 0.f;
#pragma unroll
            for (int r = 0; r < 4; ++r) {
                const int row = m0 + wm * (BM / 2) + mf * 16 + rq * 4 + r;
                float v = scale * (acc[mf][nf][r] + bv);
                const size_t idx = (size_t)row * ldc + col;
                if (res1) v += res1[idx];
                if (res2) v += res2[idx];
                if (relu) v = fmaxf(v, 0.f);
                if (Cf) Cf[idx] = v;
                if (Ch) Ch[idx] = f2bf(v);
            }
        }
}

// ---------------------------------------------------------------------------
// Split-S flash attention. Block = 64 q-rows x one S-chunk, 4 waves; wave w
// owns rows w*16..w*16+15 end-to-end (in-register softmax via shfl over the
// 16-lane ml group; per-wave-private St slice for the PV A-operand).
//
// WITHIN-64 COLUMN PERMUTATION: score col (nf,ml) [logical s = 16*nf + ml]
// is stored at PHYSICAL position p = 4*ml + nf, so each lane's 4 values per
// row are contiguous 8 bytes -> cvt_pk_bf16 pairs + one b64 store replaces
// 16 scalar stores. PV is permutation-invariant because vtrans stages V in
// the SAME physical order. probs (NEED_W) are written permuted; avg_softmax
// un-permutes (via LDS) before its coalesced final write.
//
// Each block writes UN-normalized partial O (fp32) + per-row (m,l) to
// workspace; attn_merge combines chunks. grid = (L/64, 16 bh, nchunks).
// ---------------------------------------------------------------------------
template<bool NEED_W>
__global__ __launch_bounds__(256) void attn_flash64(
    const u16* __restrict__ Q, int ldq,
    const u16* __restrict__ Kp, int ldk,
    const u16* __restrict__ vT,
    u16* __restrict__ scores,
    float* __restrict__ Of, float2* __restrict__ pml,
    int L, int S, int CS)
{
    __shared__ u16 Ks[64 * 72];
    __shared__ u16 Vt[64 * 72];
    __shared__ u16 St[4][16 * 72];

    const int tid = threadIdx.x;
    const int wave = tid >> 6, lane = tid & 63;
    const int ml = lane & 15, rq = lane >> 4;
    const int i0 = blockIdx.x * 64;
    const int bz = blockIdx.y, bb = bz & 1, hh = bz >> 1;
    const int chunk = blockIdx.z;
    const int cs0 = chunk * CS;
    u16* Sb = NEED_W ? scores + (size_t)bz * L * S + (size_t)i0 * S : nullptr;
    const u16* Vbase = vT + (size_t)bz * 64 * S;

    // Q fragments for this wave's 16 rows (one-time, direct from global)
    const int qrow = i0 + wave * 16 + ml;
    const short8 qf0 = *(const short8*)&Q[(size_t)(qrow * 2 + bb) * ldq + hh * 64 + rq * 8];
    const short8 qf1 = *(const short8*)&Q[(size_t)(qrow * 2 + bb) * ldq + hh * 64 + 32 + rq * 8];

    float mrun[4], lrun[4];
    f32x4 acc[4];
#pragma unroll
    for (int r = 0; r < 4; ++r) {
        mrun[r] = -1e30f; lrun[r] = 0.f;
        acc[r] = (f32x4){0.f, 0.f, 0.f, 0.f};
    }

    const int sr0 = tid >> 3, dc0 = (tid & 7) * 8;
    const int sr1 = (tid + 256) >> 3, dc1 = ((tid + 256) & 7) * 8;

    // prefetch first tile of this chunk into registers
    short8 kr0 = *(const short8*)&Kp[(size_t)((cs0 + sr0) * 2 + bb) * ldk + hh * 64 + dc0];
    short8 kr1 = *(const short8*)&Kp[(size_t)((cs0 + sr1) * 2 + bb) * ldk + hh * 64 + dc1];
    short8 vr0 = *(const short8*)&Vbase[(size_t)sr0 * S + cs0 + dc0];
    short8 vr1 = *(const short8*)&Vbase[(size_t)sr1 * S + cs0 + dc1];

    u16* Sw = St[wave];

    for (int k0 = cs0; k0 < cs0 + CS; k0 += 64) {
        __syncthreads();   // prev tile's Ks/Vt reads complete
        *(short8*)&Ks[sr0 * 72 + dc0] = kr0;
        *(short8*)&Ks[sr1 * 72 + dc1] = kr1;
        *(short8*)&Vt[sr0 * 72 + dc0] = vr0;
        *(short8*)&Vt[sr1 * 72 + dc1] = vr1;
        if (k0 + 64 < cs0 + CS) {
            const int kn = k0 + 64;
            kr0 = *(const short8*)&Kp[(size_t)((kn + sr0) * 2 + bb) * ldk + hh * 64 + dc0];
            kr1 = *(const short8*)&Kp[(size_t)((kn + sr1) * 2 + bb) * ldk + hh * 64 + dc1];
            vr0 = *(const short8*)&Vbase[(size_t)sr0 * S + kn + dc0];
            vr1 = *(const short8*)&Vbase[(size_t)sr1 * S + kn + dc1];
        }
        __syncthreads();   // staged tile visible

        // ---- QK^T: 4 col-fragments x (K=64 as 2 MFMAs), scores in regs
        f32x4 sc[4];
#pragma unroll
        for (int nf = 0; nf < 4; ++nf) {
            const short8 kf0 = *(const short8*)&Ks[(nf * 16 + ml) * 72 + rq * 8];
            const short8 kf1 = *(const short8*)&Ks[(nf * 16 + ml) * 72 + 32 + rq * 8];
            f32x4 s = (f32x4){0.f, 0.f, 0.f, 0.f};
            s = __builtin_amdgcn_mfma_f32_16x16x32_bf16(qf0, kf0, s, 0, 0, 0);
            s = __builtin_amdgcn_mfma_f32_16x16x32_bf16(qf1, kf1, s, 0, 0, 0);
#pragma unroll
            for (int r = 0; r < 4; ++r) s[r] *= 0.125f;
            sc[nf] = s;
        }

        // ---- stream raw bf16 scores to global, packed, permuted-within-64
        if (NEED_W) {
#pragma unroll
            for (int r = 0; r < 4; ++r) {
                const unsigned int pk0 = pk_bf16(sc[0][r], sc[1][r]);
                const unsigned int pk1 = pk_bf16(sc[2][r], sc[3][r]);
                *(uint2*)&Sb[(size_t)(wave * 16 + rq * 4 + r) * S + k0 + ml * 4] =
                    make_uint2(pk0, pk1);
            }
        }

        // ---- per-row tile max (registers + shfl over ml group)
        float tm[4];
#pragma unroll
        for (int r = 0; r < 4; ++r)
            tm[r] = fmaxf(fmaxf(sc[0][r], sc[1][r]), fmaxf(sc[2][r], sc[3][r]));
#pragma unroll
        for (int mk = 1; mk < 16; mk <<= 1)
#pragma unroll
            for (int r = 0; r < 4; ++r)
                tm[r] = fmaxf(tm[r], __shfl_xor(tm[r], mk));

        float alpha[4], mn[4];
#pragma unroll
        for (int r = 0; r < 4; ++r) {
            mn[r] = fmaxf(mrun[r], tm[r]);
            alpha[r] = __expf(mrun[r] - mn[r]);
            mrun[r] = mn[r];
        }

        // ---- exp (once), row-sum, P -> private St slice (packed, permuted)
        float rs[4];
#pragma unroll
        for (int r = 0; r < 4; ++r) {
            const float p0 = __expf(sc[0][r] - mn[r]);
            const float p1 = __expf(sc[1][r] - mn[r]);
            const float p2 = __expf(sc[2][r] - mn[r]);
            const float p3 = __expf(sc[3][r] - mn[r]);
            rs[r] = (p0 + p1) + (p2 + p3);
            const unsigned int pk0 = pk_bf16(p0, p1);
            const unsigned int pk1 = pk_bf16(p2, p3);
            *(uint2*)&Sw[(rq * 4 + r) * 72 + ml * 4] = make_uint2(pk0, pk1);
        }
#pragma unroll
        for (int mk = 1; mk < 16; mk <<= 1)
#pragma unroll
            for (int r = 0; r < 4; ++r)
                rs[r] += __shfl_xor(rs[r], mk);
#pragma unroll
        for (int r = 0; r < 4; ++r)
            lrun[r] = lrun[r] * alpha[r] + rs[r];

        // ---- O rescale + PV (A from private St, same-wave in-order DS)
#pragma unroll
        for (int df = 0; df < 4; ++df)
#pragma unroll
            for (int r = 0; r < 4; ++r)
                acc[df][r] *= alpha[r];
#pragma unroll
        for (int kc = 0; kc < 2; ++kc) {
            const short8 afr = *(const short8*)&Sw[ml * 72 + kc * 32 + rq * 8];
#pragma unroll
            for (int df = 0; df < 4; ++df) {
                const short8 bfr = *(const short8*)&Vt[(df * 16 + ml) * 72 + kc * 32 + rq * 8];
                acc[df] = __builtin_amdgcn_mfma_f32_16x16x32_bf16(afr, bfr, acc[df], 0, 0, 0);
            }
        }
    }

    // ---- write un-normalized partial O + per-row (m,l)
#pragma unroll
    for (int df = 0; df < 4; ++df)
#pragma unroll
        for (int r = 0; r < 4; ++r) {
            const int i = i0 + wave * 16 + rq * 4 + r;
            Of[((size_t)(chunk * 16 + bz) * L + i) * 64 + df * 16 + ml] = acc[df][r];
        }
    if (ml == 0) {
#pragma unroll
        for (int r = 0; r < 4; ++r)
            pml[(size_t)chunk * 16 * L + (size_t)bz * L + i0 + wave * 16 + rq * 4 + r] =
                make_float2(mrun[r], lrun[r]);
    }
}

// ---------------------------------------------------------------------------
// Merge split-S partials: att = (sum_c e^{m_c-M} O_c) / (sum_c e^{m_c-M} l_c),
// stats = (M, 1/l_total). Block of 256 handles 4 rows (64 lanes per row).
// grid = 16*L/4.
// ---------------------------------------------------------------------------
template<bool NEED_W>
__global__ __launch_bounds__(256) void attn_merge(
    const float* __restrict__ Of, const float2* __restrict__ pml,
    u16* __restrict__ att, float2* __restrict__ stats, int L, int nchunks)
{
    const int tid = threadIdx.x;
    const int g = blockIdx.x * 4 + (tid >> 6);   // row id in [0, 16*L)
    const int d = tid & 63;
    const int bz = g / L, i = g - bz * L;
    const int bb = bz & 1, hh = bz >> 1;

    float M = -1e30f;
    for (int c = 0; c < nchunks; ++c)
        M = fmaxf(M, pml[(size_t)c * 16 * L + g].x);
    float T = 0.f, O = 0.f;
    for (int c = 0; c < nchunks; ++c) {
        const float2 ml_ = pml[(size_t)c * 16 * L + g];
        const float w = __expf(ml_.x - M);
        T += ml_.y * w;
        O += w * Of[((size_t)(c * 16 + bz) * L + i) * 64 + d];
    }
    const float invT = 1.0f / T;
    att[((size_t)i * 2 + bb) * 512 + hh * 64 + d] = f2bf(O * invT);
    if (NEED_W && d == 0)
        stats[(size_t)bz * L + i] = make_float2(M, invT);
}

// ---------------------------------------------------------------------------
// One-time V transpose: vT[bh][d][tile*64+p] = V[(s*2+b)*ldv + h*64 + d]
// with logical s = tile*64 + (p>>2) + 16*(p&3)  (within-64 permutation that
// matches attn_flash64's P layout).
// ---------------------------------------------------------------------------
__global__ __launch_bounds__(256) void vtrans(
    const u16* __restrict__ V, int ldv, u16* __restrict__ vT, int S)
{
    __shared__ u16 Vs[64 * 72];
    const int tid = threadIdx.x;
    const int s0 = blockIdx.x * 64;
    const int bh = blockIdx.y, b = bh & 1, h = bh >> 1;

#pragma unroll
    for (int c = 0; c < 2; ++c) {
        const int idx = tid + c * 256;
        const int sr = idx >> 3, dc = (idx & 7) * 8;
        *(short8*)&Vs[sr * 72 + dc] =
            *(const short8*)&V[(size_t)((s0 + sr) * 2 + b) * ldv + h * 64 + dc];
    }
    __syncthreads();
#pragma unroll
    for (int c = 0; c < 2; ++c) {
        const int idx = tid + c * 256;
        const int dr = idx >> 3, sc = (idx & 7) * 8;
        short8 o;
#pragma unroll
        for (int j = 0; j < 8; ++j) {
            const int p = sc + j;
            o[j] = (short)Vs[((p >> 2) + 16 * (p & 3)) * 72 + dr];
        }
        *(short8*)&vT[(size_t)bh * 64 * S + (size_t)dr * S + s0 + sc] = o;
    }
}

// ---------------------------------------------------------------------------
// Head-average of (stats-normalized) probs from RAW scores + second softmax
// -> fp32 out (1 or 2 copies). grid = 2*L, blockIdx.x = b*L + i.
// probs are stored permuted-within-64; reads stay coalesced; the un-permute
// goes through LDS so the final global writes are coalesced float4s.
// ---------------------------------------------------------------------------
__global__ __launch_bounds__(256) void avg_softmax_f(
    const u16* __restrict__ P, const float2* __restrict__ st, int L, int S,
    float* __restrict__ out1, float* __restrict__ out2)
{
    __shared__ float red[256];
    __shared__ float stage[2048];
    const int tid = threadIdx.x;
    const bool act = tid * 8 < S;
    const int b = blockIdx.x / L, i = blockIdx.x % L;
    const size_t LS = (size_t)L * S;

    float acc[8] = {};
    if (act) {
#pragma unroll
        for (int h = 0; h < 8; ++h) {
            const int bh = h * 2 + b;
            const float2 s = st[(size_t)bh * L + i];
            const short8 r8 = *(const short8*)&P[(size_t)bh * LS + (size_t)i * S + tid * 8];
#pragma unroll
            for (int j = 0; j < 8; ++j)
                acc[j] += __expf(bf2f((u16)r8[j]) - s.x) * s.y;
        }
#pragma unroll
        for (int j = 0; j < 8; ++j) acc[j] *= 0.125f;
    }
    float lmax = -1e30f;
    if (act) {
#pragma unroll
        for (int j = 0; j < 8; ++j) lmax = fmaxf(lmax, acc[j]);
    }
    red[tid] = lmax; __syncthreads();
    for (int s = 128; s; s >>= 1) {
        if (tid < s) red[tid] = fmaxf(red[tid], red[tid + s]);
        __syncthreads();
    }
    const float mx = red[0]; __syncthreads();
    float e[8];
    float ls = 0.f;
    if (act) {
#pragma unroll
        for (int j = 0; j < 8; ++j) { e[j] = __expf(acc[j] - mx); ls += e[j]; }
    }
    red[tid] = ls; __syncthreads();
    for (int s = 128; s; s >>= 1) {
        if (tid < s) red[tid] += red[tid + s];
        __syncthreads();
    }
    const float inv = 1.0f / red[0];
    if (act) {
        // un-permute into LDS: physical p = (tid&7)*8+j within 64-group
        const int g64 = (tid >> 3) * 64;
        const int t2 = (tid & 7) * 2;
#pragma unroll
        for (int j = 0; j < 8; ++j) {
            const int c = t2 + (j >> 2) + 16 * (j & 3);
            stage[g64 + c] = e[j] * inv;
        }
    }
    __syncthreads();
    const size_t base = (size_t)blockIdx.x * S;
    for (int idx = tid * 4; idx < S; idx += 1024) {
        const float4 v = *(const float4*)&stage[idx];
        *(float4*)&out1[base + idx] = v;
        if (out2) *(float4*)&out2[base + idx] = v;
    }
}

// ---------------------------------------------------------------------------
// LayerNorm over rows of 512; fp32 out + optional bf16 out.
// ---------------------------------------------------------------------------
__global__ __launch_bounds__(256) void ln512(
    const float* __restrict__ X, const float* __restrict__ g,
    const float* __restrict__ be, float* __restrict__ Yf, u16* __restrict__ Yb)
{
    __shared__ float red[256];
    const int r = blockIdx.x, tid = threadIdx.x;
    const float* xr = X + (size_t)r * 512;
    const float x0 = xr[tid], x1 = xr[tid + 256];
    red[tid] = x0 + x1; __syncthreads();
    for (int st = 128; st; st >>= 1) {
        if (tid < st) red[tid] += red[tid + st];
        __syncthreads();
    }
    const float mean = red[0] * (1.0f / 512.0f); __syncthreads();
    const float d0 = x0 - mean, d1 = x1 - mean;
    red[tid] = d0 * d0 + d1 * d1; __syncthreads();
    for (int st = 128; st; st >>= 1) {
        if (tid < st) red[tid] += red[tid + st];
        __syncthreads();
    }
    const float rstd = rsqrtf(red[0] * (1.0f / 512.0f) + LN_EPS);
    const float y0 = d0 * rstd * g[tid] + be[tid];
    const float y1 = d1 * rstd * g[tid + 256] + be[tid + 256];
    float* yr = Yf + (size_t)r * 512;
    yr[tid] = y0; yr[tid + 256] = y1;
    if (Yb) {
        u16* yb = Yb + (size_t)r * 512;
        yb[tid] = f2bf(y0); yb[tid + 256] = f2bf(y1);
    }
}

// ---------------------------------------------------------------------------
// pair assembly: inverse map + gather rows to bf16.
// ---------------------------------------------------------------------------
__global__ void init_inv(int* __restrict__ inv) {
    const int i = blockIdx.x * 256 + threadIdx.x;
    if (i < 4096) inv[i] = -1;
}
__global__ void scatter_inv(int* __restrict__ inv, const int* __restrict__ ind, int n) {
    const int i = blockIdx.x * 256 + threadIdx.x;
    if (i < n) inv[ind[i]] = i;
}
__global__ void gather_rows_bf(
    u16* __restrict__ dst, const float* __restrict__ spf,
    const float* __restrict__ ep, const int* __restrict__ ind,
    const int* __restrict__ inv, int total4)
{
    const int e = blockIdx.x * 256 + threadIdx.x;
    if (e >= total4) return;
    const int row = e >> 7, c = e & 127;
    const int j = row >> 1, b = row & 1;
    const int idx = ind[j];
    const int iv = inv[idx];
    const float4* src = (iv >= 0) ? (const float4*)(spf + (size_t)(iv * 2 + b) * 512)
                                  : (const float4*)(ep + (size_t)(idx * 2 + b) * 512);
    const float4 v = src[c];
    ushort4 o; o.x = f2bf(v.x); o.y = f2bf(v.y); o.z = f2bf(v.z); o.w = f2bf(v.w);
    ((ushort4*)dst)[e] = o;
}

// ---------------------------------------------------------------------------
extern "C" void kernel_launch(void* const* d_in, const int* in_sizes, int n_in,
                              void* d_out, int out_size, void* d_ws, size_t ws_size,
                              hipStream_t stream)
{
    (void)in_sizes; (void)n_in; (void)out_size; (void)ws_size;

    const float* in_sp = (const float*)d_in[0];
    const float* in_su = (const float*)d_in[1];
    const float* in_ep = (const float*)d_in[2];
    const int* ind_pair = (const int*)d_in[3];
    const int* ind_e2e  = (const int*)d_in[4];
    const int* ind_n2e  = (const int*)d_in[5];
    const float *Wi_sa  = (const float*)d_in[6],  *bi_sa  = (const float*)d_in[7];
    const float *Wo_sa  = (const float*)d_in[8],  *bo_sa  = (const float*)d_in[9];
    const float *Wi_san = (const float*)d_in[10], *bi_san = (const float*)d_in[11];
    const float *Wo_san = (const float*)d_in[12], *bo_san = (const float*)d_in[13];
    const float *Wi_e2e = (const float*)d_in[14], *bi_e2e = (const float*)d_in[15];
    const float *Wo_e2e = (const float*)d_in[16], *bo_e2e = (const float*)d_in[17];
    const float *Wi_n2e = (const float*)d_in[18], *bi_n2e = (const float*)d_in[19];
    const float *Wo_n2e = (const float*)d_in[20], *bo_n2e = (const float*)d_in[21];
    const float *Wi_n2n = (const float*)d_in[22], *bi_n2n = (const float*)d_in[23];
    const float *Wo_n2n = (const float*)d_in[24], *bo_n2n = (const float*)d_in[25];
    const float *W1  = (const float*)d_in[26], *b1f  = (const float*)d_in[27];
    const float *W2  = (const float*)d_in[28], *b2f  = (const float*)d_in[29];
    const float *W1u = (const float*)d_in[30], *b1fu = (const float*)d_in[31];
    const float *W2u = (const float*)d_in[32], *b2fu = (const float*)d_in[33];
    const float *g1  = (const float*)d_in[34], *g1u = (const float*)d_in[35];
    const float *g2  = (const float*)d_in[36], *g3  = (const float*)d_in[37];
    const float *be1 = (const float*)d_in[38], *be1u = (const float*)d_in[39];
    const float *be2 = (const float*)d_in[40], *be3  = (const float*)d_in[41];

    float* Wf = (float*)d_ws;
    size_t of = 0;
    auto af_ = [&](size_t n) { float* p = Wf + of; of += n; return p; };
    float* spf    = af_((size_t)2048 * 512);
    float* suf    = af_((size_t)512 * 512);
    float* tmp0f  = af_((size_t)2048 * 512);
    float* tmp1f  = af_((size_t)2048 * 512);
    float* upn2ef = af_((size_t)512 * 512);
    float2* stats = (float2*)af_((size_t)2 * 16 * 1024);
    float* Ofp    = af_((size_t)4096 * 16 * 64);          // split-S partial O
    float2* pml   = (float2*)af_((size_t)2 * 4096 * 16);  // split-S partial (m,l)

    u16* Wu = (u16*)(Wf + of);
    size_t ou = 0;
    auto au_ = [&](size_t n) { u16* p = Wu + ou; ou += n; return p; };
    u16* in_spb = au_((size_t)2048 * 512);
    u16* in_sub = au_((size_t)512 * 512);
    u16* spb    = au_((size_t)2048 * 512);
    u16* sub    = au_((size_t)512 * 512);
    u16* ge2eb  = au_((size_t)4096 * 512);
    u16* gn2eb  = au_((size_t)4096 * 512);
    u16* qkvb   = au_((size_t)2048 * 1536);
    u16* kvb    = au_((size_t)4096 * 1024);
    u16* attb   = au_((size_t)2048 * 512);
    u16* tmp1b  = au_((size_t)2048 * 512);
    u16* ffnb   = au_((size_t)2048 * 2048);
    u16* vtb    = au_((size_t)16 * 64 * 2048);
    u16* probs  = au_((size_t)16 * 1024 * 2048);
    u16* wb[14];
    const int wsz[14] = {786432, 262144, 786432, 262144, 786432, 262144, 786432,
                         262144, 786432, 262144, 1048576, 1048576, 1048576, 1048576};
    for (int i = 0; i < 14; ++i) wb[i] = au_((size_t)wsz[i]);
    int* inv = (int*)(Wu + ou);

    float* out_uu = (float*)d_out;
    float* out_up = out_uu + 262144;
    float* out_w1 = out_up + 1048576;
    float* out_w2 = out_w1 + 4194304;
    float* out_w3 = out_w2 + 4194304;
    float* out_w4 = out_w3 + 1048576;

    const dim3 blk(256);

    CvtDesc cd;
    const float* wsrc[14] = {Wi_sa, Wo_sa, Wi_san, Wo_san, Wi_e2e, Wo_e2e, Wi_n2e,
                             Wo_n2e, Wi_n2n, Wo_n2n, W1, W2, W1u, W2u};
    for (int i = 0; i < 14; ++i) { cd.src[i] = wsrc[i]; cd.dst[i] = wb[i]; cd.n4[i] = wsz[i] / 4; }
    cd.src[14] = in_sp; cd.dst[14] = in_spb; cd.n4[14] = 1048576 / 4;
    cd.src[15] = in_su; cd.dst[15] = in_sub; cd.n4[15] = 262144 / 4;
    cvt_multi<<<dim3(1024, 16), blk, 0, stream>>>(cd);

    init_inv<<<16, blk, 0, stream>>>(inv);
    scatter_inv<<<4, blk, 0, stream>>>(inv, ind_pair, 1024);

    auto gemm = [&](int tile, const u16* A, int lda, const u16* B, int ldb,
                    float* Cf, u16* Ch, int ldc,
                    const float* bias, const float* r1, const float* r2,
                    float scale, int relu, int M, int N, int K) {
        if (tile == 64)
            mfma_gemm<64, 64><<<dim3(N / 64, M / 64), blk, 0, stream>>>(
                A, lda, B, ldb, Cf, Ch, ldc, bias, r1, r2, scale, relu, K);
        else
            mfma_gemm<128, 128><<<dim3(N / 128, M / 128), blk, 0, stream>>>(
                A, lda, B, ldb, Cf, Ch, ldc, bias, r1, r2, scale, relu, K);
    };
    // attention core: vtrans + split-S flash + merge
    auto attn = [&](const u16* Q, int ldq, const u16* Kp, int ldk,
                    const u16* V, int ldv, int L, int S, bool needW, int nchunks) {
        vtrans<<<dim3(S / 64, 16), blk, 0, stream>>>(V, ldv, vtb, S);
        const int CS = S / nchunks;
        const dim3 g(L / 64, 16, nchunks);
        const dim3 m(16 * L / 4);
        if (needW) {
            attn_flash64<true><<<g, blk, 0, stream>>>(
                Q, ldq, Kp, ldk, vtb, probs, Ofp, pml, L, S, CS);
            attn_merge<true><<<m, blk, 0, stream>>>(Ofp, pml, attb, stats, L, nchunks);
        } else {
            attn_flash64<false><<<g, blk, 0, stream>>>(
                Q, ldq, Kp, ldk, vtb, nullptr, Ofp, pml, L, S, CS);
            attn_merge<false><<<m, blk, 0, stream>>>(Ofp, pml, attb, nullptr, L, nchunks);
        }
    };

    // ================= self-attention (pair) =================
    gemm(128, in_spb, 512, wb[0], 512, nullptr, qkvb, 1536,
         bi_sa, nullptr, nullptr, 1.f, 0, 2048, 1536, 512);
    attn(qkvb, 1536, qkvb + 512, 1536, qkvb + 1024, 1536, 1024, 1024, false, 4);
    gemm(64, attb, 512, wb[1], 512, tmp0f, nullptr, 512,
         bo_sa, in_sp, nullptr, 1.f, 0, 2048, 512, 512);
    ln512<<<2048, blk, 0, stream>>>(tmp0f, g1, be1, spf, spb);

    // ================= self-attention (unary) =================
    gemm(64, in_sub, 512, wb[2], 512, nullptr, qkvb, 1536,
         bi_san, nullptr, nullptr, 1.f, 0, 512, 1536, 512);
    attn(qkvb, 1536, qkvb + 512, 1536, qkvb + 1024, 1536, 256, 256, false, 4);
    gemm(64, attb, 512, wb[3], 512, tmp0f, nullptr, 512,
         bo_san, in_su, nullptr, 1.f, 0, 512, 512, 512);
    ln512<<<512, blk, 0, stream>>>(tmp0f, g1u, be1u, suf, sub);

    // ================= gathers =================
    gather_rows_bf<<<2048, blk, 0, stream>>>(ge2eb, spf, in_ep, ind_e2e, inv, 524288);
    gather_rows_bf<<<2048, blk, 0, stream>>>(gn2eb, spf, in_ep, ind_n2e, inv, 524288);

    // ================= e2e cross-attention =================
    gemm(64, spb, 512, wb[4], 512, nullptr, qkvb, 512,
         bi_e2e, nullptr, nullptr, 1.f, 0, 2048, 512, 512);
    gemm(128, ge2eb, 512, wb[4] + 262144, 512, nullptr, kvb, 1024,
         bi_e2e + 512, nullptr, nullptr, 1.f, 0, 4096, 1024, 512);
    attn(qkvb, 512, kvb, 1024, kvb + 512, 1024, 1024, 2048, true, 4);
    avg_softmax_f<<<2048, blk, 0, stream>>>(probs, stats, 1024, 2048, out_w1, out_w2);
    gemm(64, attb, 512, wb[5], 512, tmp0f, nullptr, 512,
         bo_e2e, spf, nullptr, 2.f, 0, 2048, 512, 512);
    ln512<<<2048, blk, 0, stream>>>(tmp0f, g2, be2, tmp1f, tmp1b);
    // FFN (pair)
    gemm(128, tmp1b, 512, wb[10], 512, nullptr, ffnb, 2048,
         b1f, nullptr, nullptr, 1.f, 1, 2048, 2048, 512);
    gemm(64, ffnb, 2048, wb[11], 2048, tmp0f, nullptr, 512,
         b2f, tmp1f, nullptr, 1.f, 0, 2048, 512, 2048);
    ln512<<<2048, blk, 0, stream>>>(tmp0f, g3, be3, out_up, nullptr);

    // ================= n2e cross-attention =================
    gemm(64, sub, 512, wb[6], 512, nullptr, qkvb, 512,
         bi_n2e, nullptr, nullptr, 1.f, 0, 512, 512, 512);
    gemm(128, gn2eb, 512, wb[6] + 262144, 512, nullptr, kvb, 1024,
         bi_n2e + 512, nullptr, nullptr, 1.f, 0, 4096, 1024, 512);
    attn(qkvb, 512, kvb, 1024, kvb + 512, 1024, 256, 2048, true, 16);
    avg_softmax_f<<<512, blk, 0, stream>>>(probs, stats, 256, 2048, out_w3, nullptr);
    gemm(64, attb, 512, wb[7], 512, upn2ef, nullptr, 512,
         bo_n2e, nullptr, nullptr, 1.f, 0, 512, 512, 512);

    // ================= n2n self-attention =================
    gemm(64, sub, 512, wb[8], 512, nullptr, qkvb, 1536,
         bi_n2n, nullptr, nullptr, 1.f, 0, 512, 1536, 512);
    attn(qkvb, 1536, qkvb + 512, 1536, qkvb + 1024, 1536, 256, 256, true, 4);
    avg_softmax_f<<<512, blk, 0, stream>>>(probs, stats, 256, 256, out_w4, nullptr);
    gemm(64, attb, 512, wb[9], 512, tmp0f, nullptr, 512,
         bo_n2n, suf, upn2ef, 1.f, 0, 512, 512, 512);
    ln512<<<512, blk, 0, stream>>>(tmp0f, g2, be2, tmp1f, tmp1b);
    // FFN (unary)
    gemm(64, tmp1b, 512, wb[12], 512, nullptr, ffnb, 2048,
         b1fu, nullptr, nullptr, 1.f, 1, 512, 2048, 512);
    gemm(64, ffnb, 2048, wb[13], 2048, tmp0f, nullptr, 512,
         b2fu, tmp1f, nullptr, 1.f, 0, 512, 512, 2048);
    ln512<<<512, blk, 0, stream>>>(tmp0f, g3, be3, out_uu, nullptr);
}